// Round 5
// baseline (33257.031 us; speedup 1.0000x reference)
//
#include <hip/hip_runtime.h>
#include <hip/hip_cooperative_groups.h>
#include <math.h>

namespace cg = cooperative_groups;

#define DIM   768
#define NHEAD 16
#define DHEAD 48
#define NLAY  3
#define NTOK  256
#define BATCH 4
#define NPAST_ 16
#define NFUT  20
#define CCTX  273              // NTOK + 1 + NPAST
#define SMAXT 293              // CCTX + NFUT
#define MROWS 1172             // BATCH * SMAXT
#define NEGV  (-1.0e9f)
#define QKVPLANE 900096        // BATCH*NHEAD*SMAXT*48
#define SMEM_BYTES 36864

typedef unsigned short u16;
typedef unsigned int   u32;
typedef __attribute__((ext_vector_type(8))) short short8;
typedef __attribute__((ext_vector_type(4))) float floatx4;

__device__ inline u16 f2bf(float x) {
    union { float f; u32 u; } v; v.f = x;
    u32 r = v.u + 0x7fffu + ((v.u >> 16) & 1u);
    return (u16)(r >> 16);
}

__device__ inline float gelu_f(float x) {
    return 0.5f * x * (1.0f + erff(x * 0.70710678118654752f));
}

// ---------------------------------------------------------------- init X_base (separate kernel)
__global__ void init_base(const float* __restrict__ img, const float* __restrict__ past,
                          const int* __restrict__ intent, const float* __restrict__ pos,
                          const float* __restrict__ futq, const float* __restrict__ iemb,
                          const float* __restrict__ temb, const float* __restrict__ Wp,
                          const float* __restrict__ bp, const float* __restrict__ Wpp,
                          const float* __restrict__ bpp, float* __restrict__ X)
{
    int r = blockIdx.x;
    int b = r / SMAXT, s = r % SMAXT;
    for (int j = threadIdx.x; j < DIM; j += blockDim.x) {
        float v;
        if (s < NTOK) {
            v = img[(long)(b * NTOK + s) * DIM + j] + pos[(long)s * DIM + j];
        } else if (s == NTOK) {
            int idx = intent[b] - 1; idx = idx < 0 ? 0 : (idx > 2 ? 2 : idx);
            v = iemb[(long)idx * DIM + j];
        } else if (s < CCTX) {
            int i = s - (NTOK + 1);
            v = bp[j] + bpp[j] + temb[(long)i * DIM + j];
            const float* pr = past + (long)(b * NPAST_ + i) * 6;
            #pragma unroll
            for (int c = 0; c < 6; ++c) v += pr[c] * Wp[(long)c * DIM + j];
            v += pr[0] * Wpp[j] + pr[1] * Wpp[DIM + j];
        } else {
            int f = s - CCTX;
            v = futq[(long)f * DIM + j] + temb[(long)(NPAST_ + f) * DIM + j];
        }
        X[(long)r * DIM + j] = v;
    }
}

// ---------------------------------------------------------------- weight convert+transpose (separate kernel)
__global__ void convert_transpose(const float* __restrict__ W, u16* __restrict__ Wt, int K, int N)
{
    __shared__ float tile[32][33];
    long lstride = (long)K * N;
    W  += blockIdx.z * lstride;
    Wt += blockIdx.z * lstride;
    int n0 = blockIdx.x * 32, k0 = blockIdx.y * 32;
    int tx = threadIdx.x & 31, ty = threadIdx.x >> 5;
    for (int i = ty; i < 32; i += 8)
        tile[i][tx] = W[(long)(k0 + i) * N + n0 + tx];
    __syncthreads();
    for (int i = ty; i < 32; i += 8)
        Wt[(long)(n0 + i) * K + k0 + tx] = f2bf(tile[tx][i]);
}

// ================================================================ device stages

// ---- layernorm: one wave per row, fp32 in -> bf16 out
__device__ void ln_stage(const float* __restrict__ x, const float* __restrict__ g,
                         const float* __restrict__ be, u16* __restrict__ y)
{
    int gw = blockIdx.x * 4 + (threadIdx.x >> 6);
    int lane = threadIdx.x & 63;
    int stride = gridDim.x * 4;
    for (int row = gw; row < MROWS; row += stride) {
        const float* xr = x + (long)row * DIM;
        float v[12];
        float s = 0.f;
        #pragma unroll
        for (int i = 0; i < 12; ++i) { v[i] = xr[lane + 64 * i]; s += v[i]; }
        #pragma unroll
        for (int off = 32; off; off >>= 1) s += __shfl_down(s, off, 64);
        s = __shfl(s, 0, 64);
        float mean = s * (1.f / 768.f);
        float vs = 0.f;
        #pragma unroll
        for (int i = 0; i < 12; ++i) { float d = v[i] - mean; vs += d * d; }
        #pragma unroll
        for (int off = 32; off; off >>= 1) vs += __shfl_down(vs, off, 64);
        vs = __shfl(vs, 0, 64);
        float inv = rsqrtf(vs * (1.f / 768.f) + 1e-5f);
        u16* yr = y + (long)row * DIM;
        #pragma unroll
        for (int i = 0; i < 12; ++i) {
            int j = lane + 64 * i;
            yr[j] = f2bf((v[i] - mean) * inv * g[j] + be[j]);
        }
    }
}

// ---- bf16 MFMA GEMM stage: 64x64 tiles, BK=64, single-buffered, grid-stride over tiles
// MODE 0: out fp32 = acc + bias + res(fp32)
// MODE 1: out bf16 = relu(acc + bias)
// MODE 2: out fp32 qkv-permuted [which][b*16+h][s][48], q pre-scaled
template<int MODE>
__device__ void gemm_stage(char* smem, const u16* __restrict__ A, const u16* __restrict__ Wt,
                           const float* __restrict__ bias, const float* __restrict__ res,
                           void* __restrict__ outv, int M, int N, int K)
{
    u16* As = (u16*)smem;            // 64*64 bf16 = 8 KB
    u16* Bs = (u16*)smem + 4096;     // 64*64 bf16 = 8 KB
    const int tid = threadIdx.x, lane = tid & 63, w = tid >> 6;
    const int wm = w & 1, wn = w >> 1;
    const int lm = lane & 15, lk = lane >> 4;
    const int ntm = (M + 63) >> 6, ntn = N >> 6;
    const int ntiles = ntm * ntn;

    for (int tile = blockIdx.x; tile < ntiles; tile += gridDim.x) {
        int tm = tile % ntm, tn = tile / ntm;
        int m0 = tm << 6, n0 = tn << 6;

        floatx4 acc[2][2];
        #pragma unroll
        for (int i = 0; i < 2; ++i)
            #pragma unroll
            for (int j = 0; j < 2; ++j) acc[i][j] = (floatx4){0.f, 0.f, 0.f, 0.f};

        for (int k0 = 0; k0 < K; k0 += 64) {
            short8 ra[2], rb[2];
            #pragma unroll
            for (int q = 0; q < 2; ++q) {
                int c = q * 256 + tid;
                int hi = c >> 6, l6 = c & 63;
                int sub = hi & 3, tg = hi >> 2;
                int row = sub * 16 + (l6 & 15);
                int kk = tg * 32 + (l6 >> 4) * 8;
                int gra = m0 + row; if (gra >= M) gra = M - 1;
                ra[q] = *(const short8*)(A + (long)gra * K + k0 + kk);
                rb[q] = *(const short8*)(Wt + (long)(n0 + row) * K + k0 + kk);
            }
            __syncthreads();
            #pragma unroll
            for (int q = 0; q < 2; ++q) {
                int c = q * 256 + tid;
                *(short8*)&As[c * 8] = ra[q];
                *(short8*)&Bs[c * 8] = rb[q];
            }
            __syncthreads();
            #pragma unroll
            for (int tg = 0; tg < 2; ++tg) {
                short8 af[2], bf[2];
                #pragma unroll
                for (int i = 0; i < 2; ++i)
                    af[i] = *(const short8*)&As[((tg * 4 + wm * 2 + i) * 64 + lk * 16 + lm) * 8];
                #pragma unroll
                for (int j = 0; j < 2; ++j)
                    bf[j] = *(const short8*)&Bs[((tg * 4 + wn * 2 + j) * 64 + lk * 16 + lm) * 8];
                #pragma unroll
                for (int i = 0; i < 2; ++i)
                    #pragma unroll
                    for (int j = 0; j < 2; ++j)
                        acc[i][j] = __builtin_amdgcn_mfma_f32_16x16x32_bf16(af[i], bf[j], acc[i][j], 0, 0, 0);
            }
        }

        #pragma unroll
        for (int j = 0; j < 2; ++j) {
            int col = n0 + wn * 32 + j * 16 + lm;
            float bv = bias[col];
            #pragma unroll
            for (int i = 0; i < 2; ++i) {
                #pragma unroll
                for (int rr = 0; rr < 4; ++rr) {
                    int row = m0 + wm * 32 + i * 16 + lk * 4 + rr;
                    if (row >= M) continue;
                    float val = acc[i][j][rr] + bv;
                    if (MODE == 0) {
                        val += res[(long)row * N + col];
                        ((float*)outv)[(long)row * N + col] = val;
                    } else if (MODE == 1) {
                        ((u16*)outv)[(long)row * N + col] = f2bf(fmaxf(val, 0.f));
                    } else {
                        int which = col >= 1536 ? 2 : (col >= 768 ? 1 : 0);
                        int rem = col - which * 768;
                        int h = rem / 48, d = rem - h * 48;
                        if (which == 0) val *= 0.14433756729740643f;
                        int b2 = row / SMAXT, s = row - b2 * SMAXT;
                        ((float*)outv)[(long)which * QKVPLANE + ((long)(b2 * 16 + h) * SMAXT + s) * 48 + d] = val;
                    }
                }
            }
        }
    }
}

// ---- attention stage (fp32 head-major qkv, q pre-scaled); unit = (bh, 16-q-row tile)
__device__ void attn_stage(char* smem, const float* __restrict__ qkv, u16* __restrict__ o, int S)
{
    float* qs   = (float*)smem;          // 16*48
    float* kbuf = qs + 768;              // 3328
    float* sc   = kbuf + 3328;           // 16*304
    int t = threadIdx.x;
    int nqt = (S + 15) / 16;
    int nunits = 64 * nqt;

    for (int u = blockIdx.x; u < nunits; u += gridDim.x) {
        int qt = u / 64, bh = u % 64;
        int b = bh >> 4, h = bh & 15;
        int q0 = qt * 16;
        const float* qp = qkv + (long)bh * SMAXT * 48;
        const float* kp = qp + QKVPLANE;
        const float* vp = qp + 2 * QKVPLANE;

        __syncthreads();   // protect qs/sc vs previous unit's reads
        for (int lin = t; lin < 16 * 48; lin += 256) {
            int i2 = lin / 48, d = lin % 48;
            int qi2 = q0 + i2; if (qi2 > S - 1) qi2 = S - 1;
            qs[i2 * 48 + d] = qp[(long)qi2 * 48 + d];
        }
        __syncthreads();
        int i = t >> 4, j = t & 15;
        int qi = q0 + i;
        float4 q4[12];
        #pragma unroll
        for (int k4 = 0; k4 < 12; ++k4) q4[k4] = *(const float4*)&qs[i * 48 + k4 * 4];

        for (int s0 = 0; s0 < S; s0 += 64) {
            int ns = S - s0; if (ns > 64) ns = 64;
            __syncthreads();
            for (int lin = t; lin < 64 * 12; lin += 256) {
                int ss = lin / 12, d4 = lin % 12;
                float4 kv = make_float4(0.f, 0.f, 0.f, 0.f);
                if (ss < ns) kv = *(const float4*)(kp + (long)(s0 + ss) * 48 + d4 * 4);
                *(float4*)&kbuf[ss * 52 + d4 * 4] = kv;
            }
            __syncthreads();
            #pragma unroll
            for (int uu = 0; uu < 4; ++uu) {
                int ss = j + 16 * uu;
                float acc = 0.f;
                #pragma unroll
                for (int k4 = 0; k4 < 12; ++k4) {
                    float4 kk = *(const float4*)&kbuf[ss * 52 + k4 * 4];
                    acc += q4[k4].x * kk.x + q4[k4].y * kk.y + q4[k4].z * kk.z + q4[k4].w * kk.w;
                }
                int s = s0 + ss;
                if (ss < ns) {
                    bool masked = (qi >= CCTX) && (s > qi);
                    sc[i * 304 + s] = masked ? acc + NEGV : acc;
                }
            }
        }
        __syncthreads();

        float mx = -1e30f;
        for (int s = j; s < S; s += 16) mx = fmaxf(mx, sc[i * 304 + s]);
        #pragma unroll
        for (int m = 8; m; m >>= 1) mx = fmaxf(mx, __shfl_xor(mx, m, 16));
        int Sp = (S + 3) & ~3;
        float sum = 0.f;
        for (int s = j; s < Sp; s += 16) {
            float e = (s < S) ? __expf(sc[i * 304 + s] - mx) : 0.f;
            sc[i * 304 + s] = e; sum += e;
        }
        #pragma unroll
        for (int m = 8; m; m >>= 1) sum += __shfl_xor(sum, m, 16);
        float inv = 1.f / sum;

        float oc0 = 0.f, oc1 = 0.f, oc2 = 0.f;
        int d0 = j * 3;
        for (int s0 = 0; s0 < S; s0 += 64) {
            int ns4 = Sp - s0; if (ns4 > 64) ns4 = 64;
            __syncthreads();
            for (int lin = t; lin < 64 * 48; lin += 256) {
                int ss = lin / 48, d = lin % 48;
                float v = 0.f;
                int s = s0 + ss;
                if (s < S) v = vp[(long)s * 48 + d];
                kbuf[d * 68 + ss] = v;
            }
            __syncthreads();
            for (int sb = 0; sb < ns4; sb += 4) {
                float4 a4 = *(const float4*)&sc[i * 304 + s0 + sb];
                float4 v0 = *(const float4*)&kbuf[d0 * 68 + sb];
                float4 v1 = *(const float4*)&kbuf[(d0 + 1) * 68 + sb];
                float4 v2 = *(const float4*)&kbuf[(d0 + 2) * 68 + sb];
                oc0 += a4.x * v0.x + a4.y * v0.y + a4.z * v0.z + a4.w * v0.w;
                oc1 += a4.x * v1.x + a4.y * v1.y + a4.z * v1.z + a4.w * v1.w;
                oc2 += a4.x * v2.x + a4.y * v2.y + a4.z * v2.z + a4.w * v2.w;
            }
        }
        if (qi < S) {
            u16* orow = o + ((long)(b * SMAXT + qi)) * 768 + h * 48 + d0;
            orow[0] = f2bf(oc0 * inv); orow[1] = f2bf(oc1 * inv); orow[2] = f2bf(oc2 * inv);
        }
    }
}

// ---- decoder gelu GEMM stage: unit = (b, jb); 48 units
__device__ void dec_gelu_stage(char* smem, const float* __restrict__ src, long srowstride,
                               const float* __restrict__ W, const float* __restrict__ bias,
                               float* __restrict__ dst)
{
    float* s0buf = (float*)smem;       // 768
    float* red   = s0buf + 768;        // 4*64
    int tid = threadIdx.x;
    for (int u = blockIdx.x; u < 48; u += gridDim.x) {
        int b = u / 12, jb = u % 12;
        __syncthreads();
        const float* sr = src + (long)b * srowstride;
        for (int i = tid; i < 768; i += 256) s0buf[i] = sr[i];
        __syncthreads();
        int jj = tid & 63, ig = tid >> 6;
        int jcol = jb * 64 + jj;
        float acc = 0.f;
        const float* wp = W + (long)(ig * 192) * 768 + jcol;
        #pragma unroll 4
        for (int i = 0; i < 192; ++i) acc += s0buf[ig * 192 + i] * wp[(long)i * 768];
        red[ig * 64 + jj] = acc;
        __syncthreads();
        if (ig == 0) {
            float a = red[jj] + red[64 + jj] + red[128 + jj] + red[192 + jj] + bias[jcol];
            dst[(long)b * 768 + jcol] = gelu_f(a);
        }
    }
}

// ---- decoder final stage: blocks 0..3
__device__ void dec_final_stage(char* smem, const float* __restrict__ d2, const float* __restrict__ Wd3,
                                const float* __restrict__ bd3, const float* __restrict__ Wpp,
                                const float* __restrict__ bpp, const float* __restrict__ gpp,
                                const float* __restrict__ bepp, float* __restrict__ out,
                                float* __restrict__ X, int t)
{
    if (blockIdx.x >= 4) return;
    float* red = (float*)smem;     // 2*4
    float* pp  = red + 8;          // 2
    int b = blockIdx.x;
    int tid = threadIdx.x;
    const float* dr = d2 + (long)b * 768;
    float a0 = 0.f, a1 = 0.f;
    for (int i = tid; i < 768; i += 256) {
        float v = dr[i];
        a0 += v * Wd3[2 * i]; a1 += v * Wd3[2 * i + 1];
    }
    #pragma unroll
    for (int off = 32; off; off >>= 1) { a0 += __shfl_down(a0, off, 64); a1 += __shfl_down(a1, off, 64); }
    int wid = tid >> 6, lane = tid & 63;
    __syncthreads();
    if (!lane) { red[wid] = a0; red[4 + wid] = a1; }
    __syncthreads();
    if (!tid) {
        float p0 = red[0] + red[1] + red[2] + red[3] + bd3[0];
        float p1 = red[4] + red[5] + red[6] + red[7] + bd3[1];
        out[(long)(b * NFUT + t) * 2 + 0] = p0;
        out[(long)(b * NFUT + t) * 2 + 1] = p1;
        pp[0] = p0; pp[1] = p1;
    }
    __syncthreads();
    if (t < NFUT - 1) {
        float p0 = pp[0], p1 = pp[1];
        float pv[3]; float s = 0.f;
        #pragma unroll
        for (int u = 0; u < 3; ++u) {
            int jcol = tid + 256 * u;
            pv[u] = p0 * Wpp[jcol] + p1 * Wpp[768 + jcol] + bpp[jcol];
            s += pv[u];
        }
        #pragma unroll
        for (int off = 32; off; off >>= 1) s += __shfl_down(s, off, 64);
        __syncthreads();
        if (!lane) red[wid] = s;
        __syncthreads();
        float mean = (red[0] + red[1] + red[2] + red[3]) * (1.f / 768.f);
        float vs = 0.f;
        #pragma unroll
        for (int u = 0; u < 3; ++u) { float d = pv[u] - mean; vs += d * d; }
        #pragma unroll
        for (int off = 32; off; off >>= 1) vs += __shfl_down(vs, off, 64);
        __syncthreads();
        if (!lane) red[4 + wid] = vs;
        __syncthreads();
        float var = (red[4] + red[5] + red[6] + red[7]) * (1.f / 768.f);
        float inv = rsqrtf(var + 1e-5f);
        float* Xr = X + ((long)(b * SMAXT + CCTX + t + 1)) * 768;
        #pragma unroll
        for (int u = 0; u < 3; ++u) {
            int jcol = tid + 256 * u;
            float y = (pv[u] - mean) * inv * gpp[jcol] + bepp[jcol];
            if (y > 0.f) Xr[jcol] += y;
        }
    }
}

// ================================================================ mega kernel
struct MegaParams {
    float* Xb; float* xbuf; float* qkvbuf; u16* hbuf; u16* aobuf; u16* big;
    float* d1ws; float* d2ws;
    const u16* WqkvT; const u16* WoT; const u16* W1T; const u16* W2T;
    const float* bqkv; const float* bo; const float* bf1; const float* bf2;
    const float* g1; const float* beta1; const float* g2; const float* beta2;
    const float* Wd1; const float* bd1; const float* Wd2; const float* bd2;
    const float* Wd3; const float* bd3;
    const float* Wpp; const float* bpp; const float* gpp; const float* bepp;
    float* out;
};

__launch_bounds__(256, 2)
__global__ void mega(MegaParams p)
{
    __shared__ __align__(16) char smem[SMEM_BYTES];
    cg::grid_group g = cg::this_grid();

    for (int t = 0; t < NFUT; ++t) {
        int S = CCTX + t + 1;
        const float* src = p.Xb;
        for (int l = 0; l < NLAY; ++l) {
            ln_stage(src, p.g1 + l * 768, p.beta1 + l * 768, p.hbuf);
            g.sync();
            gemm_stage<2>(smem, p.hbuf, p.WqkvT + (long)l * 768 * 2304, p.bqkv + l * 2304,
                          nullptr, p.qkvbuf, MROWS, 2304, 768);
            g.sync();
            attn_stage(smem, p.qkvbuf, p.aobuf, S);
            g.sync();
            gemm_stage<0>(smem, p.aobuf, p.WoT + (long)l * 768 * 768, p.bo + l * 768,
                          src, p.xbuf, MROWS, 768, 768);
            g.sync();
            ln_stage(p.xbuf, p.g2 + l * 768, p.beta2 + l * 768, p.hbuf);
            g.sync();
            gemm_stage<1>(smem, p.hbuf, p.W1T + (long)l * 768 * 3072, p.bf1 + l * 3072,
                          nullptr, p.big, MROWS, 3072, 768);
            g.sync();
            gemm_stage<0>(smem, p.big, p.W2T + (long)l * 3072 * 768, p.bf2 + l * 768,
                          p.xbuf, p.xbuf, MROWS, 768, 3072);
            g.sync();
            src = p.xbuf;
        }
        dec_gelu_stage(smem, p.xbuf + (long)(S - 1) * 768, (long)SMAXT * 768, p.Wd1, p.bd1, p.d1ws);
        g.sync();
        dec_gelu_stage(smem, p.d1ws, 768L, p.Wd2, p.bd2, p.d2ws);
        g.sync();
        dec_final_stage(smem, p.d2ws, p.Wd3, p.bd3, p.Wpp, p.bpp, p.gpp, p.bepp, p.out, p.Xb, t);
        g.sync();
    }
}

// ---------------------------------------------------------------- launch
extern "C" void kernel_launch(void* const* d_in, const int* in_sizes, int n_in,
                              void* d_out, int out_size, void* d_ws, size_t ws_size,
                              hipStream_t stream)
{
    const float* img    = (const float*)d_in[0];
    const float* past   = (const float*)d_in[1];
    const int*   intent = (const int*)d_in[2];
    const float* pos    = (const float*)d_in[3];
    const float* futq   = (const float*)d_in[4];
    const float* iemb   = (const float*)d_in[5];
    const float* temb   = (const float*)d_in[6];
    const float* W_past = (const float*)d_in[7];
    const float* b_past = (const float*)d_in[8];
    const float* W_ppos = (const float*)d_in[9];
    const float* b_ppos = (const float*)d_in[10];
    const float* W_pp   = (const float*)d_in[11];
    const float* b_pp   = (const float*)d_in[12];
    const float* g_pp   = (const float*)d_in[13];
    const float* be_pp  = (const float*)d_in[14];
    const float* Wqkv   = (const float*)d_in[15];
    const float* bqkv   = (const float*)d_in[16];
    const float* Wo     = (const float*)d_in[17];
    const float* bo     = (const float*)d_in[18];
    const float* g1     = (const float*)d_in[19];
    const float* beta1  = (const float*)d_in[20];
    const float* g2     = (const float*)d_in[21];
    const float* beta2  = (const float*)d_in[22];
    const float* W1     = (const float*)d_in[23];
    const float* bf1    = (const float*)d_in[24];
    const float* W2     = (const float*)d_in[25];
    const float* bf2    = (const float*)d_in[26];
    const float* Wd1    = (const float*)d_in[27];
    const float* bd1    = (const float*)d_in[28];
    const float* Wd2    = (const float*)d_in[29];
    const float* bd2    = (const float*)d_in[30];
    const float* Wd3    = (const float*)d_in[31];
    const float* bd3    = (const float*)d_in[32];
    float* out = (float*)d_out;

    float* ws     = (float*)d_ws;
    float* Xb     = ws;                      // 900096 f
    float* xbuf   = ws + 900096;             // 900096 f
    float* qkvbuf = ws + 1800192;            // 2700288 f
    u16*   hbuf   = (u16*)(ws + 4500480);    // 900096 bf16
    u16*   aobuf  = (u16*)(ws + 4950528);    // 900096 bf16
    u16*   big    = (u16*)(ws + 5400576);    // 1172*3072 bf16
    float* d1ws   = ws + 7200768;            // 3072 f
    float* d2ws   = ws + 7203840;            // 3072 f
    u16*   WqkvT  = (u16*)(ws + 7206912);    // 3*2304*768 bf16
    u16*   WoT    = (u16*)(ws + 9861120);    // 3*768*768
    u16*   W1T    = (u16*)(ws + 10745856);   // 3*768*3072
    u16*   W2T    = (u16*)(ws + 14284800);   // 3*3072*768

    convert_transpose<<<dim3(2304/32, 768/32, 3), 256, 0, stream>>>(Wqkv, WqkvT, 768, 2304);
    convert_transpose<<<dim3(768/32, 768/32, 3), 256, 0, stream>>>(Wo, WoT, 768, 768);
    convert_transpose<<<dim3(3072/32, 768/32, 3), 256, 0, stream>>>(W1, W1T, 768, 3072);
    convert_transpose<<<dim3(768/32, 3072/32, 3), 256, 0, stream>>>(W2, W2T, 3072, 768);

    init_base<<<dim3(MROWS), dim3(256), 0, stream>>>(img, past, intent, pos, futq, iemb,
                                                     temb, W_past, b_past, W_ppos, b_ppos, Xb);

    MegaParams p;
    p.Xb = Xb; p.xbuf = xbuf; p.qkvbuf = qkvbuf; p.hbuf = hbuf; p.aobuf = aobuf; p.big = big;
    p.d1ws = d1ws; p.d2ws = d2ws;
    p.WqkvT = WqkvT; p.WoT = WoT; p.W1T = W1T; p.W2T = W2T;
    p.bqkv = bqkv; p.bo = bo; p.bf1 = bf1; p.bf2 = bf2;
    p.g1 = g1; p.beta1 = beta1; p.g2 = g2; p.beta2 = beta2;
    p.Wd1 = Wd1; p.bd1 = bd1; p.Wd2 = Wd2; p.bd2 = bd2;
    p.Wd3 = Wd3; p.bd3 = bd3;
    p.Wpp = W_pp; p.bpp = b_pp; p.gpp = g_pp; p.bepp = be_pp;
    p.out = out;

    int occ = 1;
    hipOccupancyMaxActiveBlocksPerMultiprocessor(&occ, (const void*)mega, 256, 0);
    if (occ < 1) occ = 1;
    hipDeviceProp_t prop;
    hipGetDeviceProperties(&prop, 0);
    int grid = occ * prop.multiProcessorCount;
    if (grid > 912) grid = 912;

    void* args[] = { &p };
    hipLaunchCooperativeKernel((void*)mega, dim3(grid), dim3(256), args, 0, stream);
}

// Round 6
// 17334.776 us; speedup vs baseline: 1.9185x; 1.9185x over previous
//
#include <hip/hip_runtime.h>
#include <math.h>

#define DIM   768
#define NHEAD 16
#define DHEAD 48
#define NLAY  3
#define NTOK  256
#define BATCH 4
#define NPAST_ 16
#define NFUT  20
#define CCTX  273              // NTOK + 1 + NPAST
#define SMAXT 293              // CCTX + NFUT
#define MROWS 1172             // BATCH * SMAXT
#define NEGV  (-1.0e9f)
#define QKVPLANE 900096        // BATCH*NHEAD*SMAXT*48

typedef unsigned short u16;
typedef unsigned int   u32;
typedef __attribute__((ext_vector_type(8))) short short8;
typedef __attribute__((ext_vector_type(4))) float floatx4;

__device__ inline u16 f2bf(float x) {
    union { float f; u32 u; } v; v.f = x;
    u32 r = v.u + 0x7fffu + ((v.u >> 16) & 1u);
    return (u16)(r >> 16);
}
__device__ inline float bf2f(u16 x) {
    union { u32 u; float f; } v; v.u = ((u32)x) << 16; return v.f;
}
__device__ inline float gelu_f(float x) {
    return 0.5f * x * (1.0f + erff(x * 0.70710678118654752f));
}

// ---------------------------------------------------------------- init X_base
__global__ void init_base(const float* __restrict__ img, const float* __restrict__ past,
                          const int* __restrict__ intent, const float* __restrict__ pos,
                          const float* __restrict__ futq, const float* __restrict__ iemb,
                          const float* __restrict__ temb, const float* __restrict__ Wp,
                          const float* __restrict__ bp, const float* __restrict__ Wpp,
                          const float* __restrict__ bpp, float* __restrict__ X)
{
    int r = blockIdx.x;
    int b = r / SMAXT, s = r % SMAXT;
    for (int j = threadIdx.x; j < DIM; j += blockDim.x) {
        float v;
        if (s < NTOK) {
            v = img[(long)(b * NTOK + s) * DIM + j] + pos[(long)s * DIM + j];
        } else if (s == NTOK) {
            int idx = intent[b] - 1; idx = idx < 0 ? 0 : (idx > 2 ? 2 : idx);
            v = iemb[(long)idx * DIM + j];
        } else if (s < CCTX) {
            int i = s - (NTOK + 1);
            v = bp[j] + bpp[j] + temb[(long)i * DIM + j];
            const float* pr = past + (long)(b * NPAST_ + i) * 6;
            #pragma unroll
            for (int c = 0; c < 6; ++c) v += pr[c] * Wp[(long)c * DIM + j];
            v += pr[0] * Wpp[j] + pr[1] * Wpp[DIM + j];
        } else {
            int f = s - CCTX;
            v = futq[(long)f * DIM + j] + temb[(long)(NPAST_ + f) * DIM + j];
        }
        X[(long)r * DIM + j] = v;
    }
}

// ---------------------------------------------------------------- weight convert + transpose: W[K,N] fp32 -> Wt[N,K] bf16
__global__ void convert_transpose(const float* __restrict__ W, u16* __restrict__ Wt, int K, int N)
{
    __shared__ float tile[32][33];
    long lstride = (long)K * N;
    W  += blockIdx.z * lstride;
    Wt += blockIdx.z * lstride;
    int n0 = blockIdx.x * 32, k0 = blockIdx.y * 32;
    int tx = threadIdx.x & 31, ty = threadIdx.x >> 5;
    for (int i = ty; i < 32; i += 8)
        tile[i][tx] = W[(long)(k0 + i) * N + n0 + tx];
    __syncthreads();
    for (int i = ty; i < 32; i += 8)
        Wt[(long)(n0 + i) * K + k0 + tx] = f2bf(tile[tx][i]);
}

// ---------------------------------------------------------------- layernorm -> bf16
__launch_bounds__(256)
__global__ void ln_kernel(const float* __restrict__ x, const float* __restrict__ g,
                          const float* __restrict__ be, u16* __restrict__ y)
{
    int row = blockIdx.x * 4 + (threadIdx.x >> 6);
    int lane = threadIdx.x & 63;
    if (row >= MROWS) return;
    const float* xr = x + (long)row * DIM;
    float v[12];
    float s = 0.f;
    #pragma unroll
    for (int i = 0; i < 12; ++i) { v[i] = xr[lane + 64 * i]; s += v[i]; }
    for (int off = 32; off; off >>= 1) s += __shfl_down(s, off, 64);
    s = __shfl(s, 0, 64);
    float mean = s * (1.f / 768.f);
    float vs = 0.f;
    #pragma unroll
    for (int i = 0; i < 12; ++i) { float d = v[i] - mean; vs += d * d; }
    for (int off = 32; off; off >>= 1) vs += __shfl_down(vs, off, 64);
    vs = __shfl(vs, 0, 64);
    float inv = rsqrtf(vs * (1.f / 768.f) + 1e-5f);
    u16* yr = y + (long)row * DIM;
    #pragma unroll
    for (int i = 0; i < 12; ++i) {
        int j = lane + 64 * i;
        yr[j] = f2bf((v[i] - mean) * inv * g[j] + be[j]);
    }
}

// ---------------------------------------------------------------- bf16 MFMA GEMM (R2-proven body)
// MODE 0: out fp32, += res.  MODE 1: relu, out bf16.  MODE 2: out fp32 qkv-permuted, q pre-scaled.
// colOff: added to col for MODE 2's which/head mapping (used by the KV-only call).
template<int BN, int MODE>
__launch_bounds__(256)
__global__ void gemm_mfma(const u16* __restrict__ A, const u16* __restrict__ Wt,
                          const float* __restrict__ bias, const float* __restrict__ res,
                          void* __restrict__ outv, int M, int N, int K, int colOff)
{
    constexpr int NSUB = BN / 16;
    constexpr int NJ = NSUB / 2;
    constexpr int NB = (BN * 8) / 256;
    __shared__ u16 As[2 * 8 * 64 * 8];       // 16 KB
    __shared__ u16 Bs[2 * NSUB * 64 * 8];    // 16 / 8 KB

    int tid = threadIdx.x;
    int lane = tid & 63;
    int w = tid >> 6, wm = w >> 1, wn = w & 1;
    int m0 = blockIdx.y * 128, n0 = blockIdx.x * BN;

    floatx4 acc[4][NJ];
    #pragma unroll
    for (int i = 0; i < 4; ++i)
        #pragma unroll
        for (int j = 0; j < NJ; ++j) acc[i][j] = (floatx4){0.f, 0.f, 0.f, 0.f};

    int lm = lane & 15, lk = lane >> 4;

    for (int k0 = 0; k0 < K; k0 += 64) {
        __syncthreads();
        #pragma unroll
        for (int i = 0; i < 4; ++i) {
            int q = tid + 256 * i;
            int r = q >> 3, c = q & 7;
            int gr = m0 + r; if (gr >= M) gr = M - 1;
            int4 v = *(const int4*)(A + (long)gr * K + k0 + c * 8);
            int off = (((c >> 2) * 8 + (r >> 4)) * 64 + (r & 15) * 4 + (c & 3)) * 8;
            *(int4*)&As[off] = v;
        }
        #pragma unroll
        for (int i = 0; i < NB; ++i) {
            int q = tid + 256 * i;
            int r = q >> 3, c = q & 7;
            int4 v = *(const int4*)(Wt + (long)(n0 + r) * K + k0 + c * 8);
            int off = (((c >> 2) * NSUB + (r >> 4)) * 64 + (r & 15) * 4 + (c & 3)) * 8;
            *(int4*)&Bs[off] = v;
        }
        __syncthreads();
        #pragma unroll
        for (int t = 0; t < 2; ++t) {
            short8 af[4];
            #pragma unroll
            for (int i = 0; i < 4; ++i)
                af[i] = *(const short8*)&As[((t * 8 + wm * 4 + i) * 64 + lm * 4 + lk) * 8];
            short8 bfr[NJ];
            #pragma unroll
            for (int j = 0; j < NJ; ++j)
                bfr[j] = *(const short8*)&Bs[((t * NSUB + wn * NJ + j) * 64 + lm * 4 + lk) * 8];
            #pragma unroll
            for (int i = 0; i < 4; ++i)
                #pragma unroll
                for (int j = 0; j < NJ; ++j)
                    acc[i][j] = __builtin_amdgcn_mfma_f32_16x16x32_bf16(af[i], bfr[j], acc[i][j], 0, 0, 0);
        }
    }

    #pragma unroll
    for (int j = 0; j < NJ; ++j) {
        int col = n0 + wn * (NJ * 16) + j * 16 + lm;
        float bv = bias[col];
        #pragma unroll
        for (int i = 0; i < 4; ++i) {
            int rbase = m0 + wm * 64 + i * 16 + lk * 4;
            #pragma unroll
            for (int rr = 0; rr < 4; ++rr) {
                int row = rbase + rr;
                if (row >= M) continue;
                float val = acc[i][j][rr] + bv;
                if (MODE == 0) {
                    val += res[(long)row * N + col];
                    ((float*)outv)[(long)row * N + col] = val;
                } else if (MODE == 1) {
                    val = fmaxf(val, 0.f);
                    ((u16*)outv)[(long)row * N + col] = f2bf(val);
                } else {
                    int gcol = col + colOff;
                    int which = gcol >= 1536 ? 2 : (gcol >= 768 ? 1 : 0);
                    int rem = gcol - which * 768;
                    int h = rem / 48, d = rem - h * 48;
                    if (which == 0) val *= 0.14433756729740643f;
                    int b2 = row / SMAXT, s = row - b2 * SMAXT;
                    ((float*)outv)[(long)which * QKVPLANE + ((long)(b2 * 16 + h) * SMAXT + s) * 48 + d] = val;
                }
            }
        }
    }
}

// ---------------------------------------------------------------- attention (layers 0,1)
__launch_bounds__(256)
__global__ void attn_kernel(const float* __restrict__ qkv, u16* __restrict__ o, int S)
{
    int bh = blockIdx.y;
    int b = bh >> 4, h = bh & 15;
    int q0 = blockIdx.x * 16;
    if (q0 >= S) return;
    __shared__ float qs[16][48];
    __shared__ float kbuf[3328];
    __shared__ float sc[16][304];
    int t = threadIdx.x;
    const float* qp = qkv + (long)bh * SMAXT * 48;
    const float* kp = qp + QKVPLANE;
    const float* vp = qp + 2 * QKVPLANE;

    for (int lin = t; lin < 16 * 48; lin += 256) {
        int i2 = lin / 48, d = lin % 48;
        int qi2 = q0 + i2; if (qi2 > S - 1) qi2 = S - 1;
        qs[i2][d] = qp[(long)qi2 * 48 + d];
    }
    __syncthreads();
    int i = t >> 4, j = t & 15;
    int qi = q0 + i;
    float4 q4[12];
    #pragma unroll
    for (int k4 = 0; k4 < 12; ++k4) q4[k4] = *(const float4*)&qs[i][k4 * 4];

    for (int s0 = 0; s0 < S; s0 += 64) {
        int ns = S - s0; if (ns > 64) ns = 64;
        __syncthreads();
        for (int lin = t; lin < 64 * 12; lin += 256) {
            int ss = lin / 12, d4 = lin % 12;
            float4 kv = make_float4(0.f, 0.f, 0.f, 0.f);
            if (ss < ns) kv = *(const float4*)(kp + (long)(s0 + ss) * 48 + d4 * 4);
            *(float4*)&kbuf[ss * 52 + d4 * 4] = kv;
        }
        __syncthreads();
        #pragma unroll
        for (int u = 0; u < 4; ++u) {
            int ss = j + 16 * u;
            float acc = 0.f;
            #pragma unroll
            for (int k4 = 0; k4 < 12; ++k4) {
                float4 kk = *(const float4*)&kbuf[ss * 52 + k4 * 4];
                acc += q4[k4].x * kk.x + q4[k4].y * kk.y + q4[k4].z * kk.z + q4[k4].w * kk.w;
            }
            int s = s0 + ss;
            if (ss < ns) {
                bool masked = (qi >= CCTX) && (s > qi);
                sc[i][s] = masked ? acc + NEGV : acc;
            }
        }
    }
    __syncthreads();

    float mx = -1e30f;
    for (int s = j; s < S; s += 16) mx = fmaxf(mx, sc[i][s]);
    #pragma unroll
    for (int m = 8; m; m >>= 1) mx = fmaxf(mx, __shfl_xor(mx, m, 16));
    int Sp = (S + 3) & ~3;
    float sum = 0.f;
    for (int s = j; s < Sp; s += 16) {
        float e = (s < S) ? __expf(sc[i][s] - mx) : 0.f;
        sc[i][s] = e; sum += e;
    }
    #pragma unroll
    for (int m = 8; m; m >>= 1) sum += __shfl_xor(sum, m, 16);
    float inv = 1.f / sum;

    float oc0 = 0.f, oc1 = 0.f, oc2 = 0.f;
    int d0 = j * 3;
    for (int s0 = 0; s0 < S; s0 += 64) {
        int ns4 = Sp - s0; if (ns4 > 64) ns4 = 64;
        __syncthreads();
        for (int lin = t; lin < 64 * 48; lin += 256) {
            int ss = lin / 48, d = lin % 48;
            float v = 0.f;
            int s = s0 + ss;
            if (s < S) v = vp[(long)s * 48 + d];
            kbuf[d * 68 + ss] = v;
        }
        __syncthreads();
        for (int sb = 0; sb < ns4; sb += 4) {
            float4 a4 = *(const float4*)&sc[i][s0 + sb];
            float4 v0 = *(const float4*)&kbuf[d0 * 68 + sb];
            float4 v1 = *(const float4*)&kbuf[(d0 + 1) * 68 + sb];
            float4 v2 = *(const float4*)&kbuf[(d0 + 2) * 68 + sb];
            oc0 += a4.x * v0.x + a4.y * v0.y + a4.z * v0.z + a4.w * v0.w;
            oc1 += a4.x * v1.x + a4.y * v1.y + a4.z * v1.z + a4.w * v1.w;
            oc2 += a4.x * v2.x + a4.y * v2.y + a4.z * v2.z + a4.w * v2.w;
        }
    }
    if (qi < S) {
        u16* orow = o + ((long)(b * SMAXT + qi)) * 768 + h * 48 + d0;
        orow[0] = f2bf(oc0 * inv); orow[1] = f2bf(oc1 * inv); orow[2] = f2bf(oc2 * inv);
    }
}

// ================================================================ layer-2 last-row specialization

// ---- q for last row only: q(b) = LN_row @ Wqkv[:, :768] + bq, scaled; grid (12,4)
__launch_bounds__(256)
__global__ void qkvq_last(const u16* __restrict__ hbuf, const u16* __restrict__ WqkvT,
                          const float* __restrict__ bqkv, float* __restrict__ qkvbuf, int S)
{
    int jb = blockIdx.x, b = blockIdx.y, tid = threadIdx.x;
    __shared__ float hrow[768];
    __shared__ float red[4][64];
    long row = (long)b * SMAXT + (S - 1);
    for (int i = tid; i < 768; i += 256) hrow[i] = bf2f(hbuf[row * 768 + i]);
    __syncthreads();
    int c = tid & 63, part = tid >> 6;
    int col = jb * 64 + c;
    const u16* wp = WqkvT + (long)col * 768 + part * 192;
    const float* hp = &hrow[part * 192];
    float a = 0.f;
    for (int k = 0; k < 192; k += 8) {
        short8 wv = *(const short8*)(wp + k);
        #pragma unroll
        for (int q = 0; q < 8; ++q) a += hp[k + q] * bf2f((u16)wv[q]);
    }
    red[part][c] = a;
    __syncthreads();
    if (part == 0) {
        float v = (red[0][c] + red[1][c] + red[2][c] + red[3][c] + bqkv[col]) * 0.14433756729740643f;
        int h = col / 48, d = col - h * 48;
        qkvbuf[((long)(b * 16 + h) * SMAXT + (S - 1)) * 48 + d] = v;
    }
}

// ---- attention for last row only: grid 64 = (b*16+h)
__launch_bounds__(256)
__global__ void attn_last(const float* __restrict__ qkv, u16* __restrict__ o, int S)
{
    int bh = blockIdx.x, b = bh >> 4, h = bh & 15;
    int tid = threadIdx.x, lane = tid & 63, w = tid >> 6;
    const float* qp = qkv + (long)bh * SMAXT * 48;
    const float* kp = qp + QKVPLANE;
    const float* vp = qp + 2 * QKVPLANE;
    __shared__ float qs[48];
    __shared__ float sc[304];
    __shared__ float redm[4], reds[4];
    __shared__ float pv[4][48];
    if (tid < 48) qs[tid] = qp[(long)(S - 1) * 48 + tid];
    __syncthreads();
    for (int s = tid; s < S; s += 256) {
        const float4* kr = (const float4*)(kp + (long)s * 48);
        float a = 0.f;
        #pragma unroll
        for (int k4 = 0; k4 < 12; ++k4) {
            float4 kk = kr[k4];
            const float* qq = &qs[k4 * 4];
            a += qq[0] * kk.x + qq[1] * kk.y + qq[2] * kk.z + qq[3] * kk.w;
        }
        sc[s] = a;   // last row attends everything: no mask
    }
    __syncthreads();
    float mx = -1e30f;
    for (int s = tid; s < S; s += 256) mx = fmaxf(mx, sc[s]);
    #pragma unroll
    for (int m = 32; m; m >>= 1) mx = fmaxf(mx, __shfl_xor(mx, m, 64));
    if (!lane) redm[w] = mx;
    __syncthreads();
    mx = fmaxf(fmaxf(redm[0], redm[1]), fmaxf(redm[2], redm[3]));
    float sum = 0.f;
    for (int s = tid; s < S; s += 256) { float e = __expf(sc[s] - mx); sc[s] = e; sum += e; }
    #pragma unroll
    for (int m = 32; m; m >>= 1) sum += __shfl_xor(sum, m, 64);
    if (!lane) reds[w] = sum;
    __syncthreads();
    float inv = 1.f / (reds[0] + reds[1] + reds[2] + reds[3]);
    int d = tid % 48, grp = tid / 48;
    if (grp < 4) {
        float a = 0.f;
        for (int s = grp; s < S; s += 4) a += sc[s] * vp[(long)s * 48 + d];
        pv[grp][d] = a;
    }
    __syncthreads();
    if (tid < 48) {
        float val = (pv[0][tid] + pv[1][tid] + pv[2][tid] + pv[3][tid]) * inv;
        o[((long)(b * SMAXT + S - 1)) * 768 + h * 48 + tid] = f2bf(val);
    }
}

// ---- Wo + residual + LN2, last row only: grid 4
__launch_bounds__(256)
__global__ void wo_ln_last(const u16* __restrict__ aobuf, const u16* __restrict__ WoT,
                           const float* __restrict__ bo, float* __restrict__ xbuf,
                           const float* __restrict__ g2, const float* __restrict__ beta2,
                           u16* __restrict__ h2buf, int S)
{
    int b = blockIdx.x, tid = threadIdx.x, lane = tid & 63, w = tid >> 6;
    long row = (long)b * SMAXT + (S - 1);
    __shared__ float ao[768];
    __shared__ float red[8];
    for (int i = tid; i < 768; i += 256) ao[i] = bf2f(aobuf[row * 768 + i]);
    __syncthreads();
    float vloc[3];
    #pragma unroll
    for (int u = 0; u < 3; ++u) {
        int col = tid + 256 * u;
        const u16* wp = WoT + (long)col * 768;
        float a = 0.f;
        for (int k = 0; k < 768; k += 8) {
            short8 wv = *(const short8*)(wp + k);
            #pragma unroll
            for (int q = 0; q < 8; ++q) a += ao[k + q] * bf2f((u16)wv[q]);
        }
        a += bo[col] + xbuf[row * 768 + col];
        xbuf[row * 768 + col] = a;
        vloc[u] = a;
    }
    float s = vloc[0] + vloc[1] + vloc[2];
    float qq = vloc[0] * vloc[0] + vloc[1] * vloc[1] + vloc[2] * vloc[2];
    #pragma unroll
    for (int o = 32; o; o >>= 1) { s += __shfl_down(s, o, 64); qq += __shfl_down(qq, o, 64); }
    __syncthreads();
    if (!lane) { red[w] = s; red[4 + w] = qq; }
    __syncthreads();
    float mean = (red[0] + red[1] + red[2] + red[3]) * (1.f / 768.f);
    float var = (red[4] + red[5] + red[6] + red[7]) * (1.f / 768.f) - mean * mean;
    float rstd = rsqrtf(var + 1e-5f);
    #pragma unroll
    for (int u = 0; u < 3; ++u) {
        int col = tid + 256 * u;
        h2buf[(long)b * 768 + col] = f2bf((vloc[u] - mean) * rstd * g2[col] + beta2[col]);
    }
}

// ---- FFN1, last row only: grid (12,4); col block of 256
__launch_bounds__(256)
__global__ void ffn1_last(const u16* __restrict__ h2buf, const u16* __restrict__ W1T,
                          const float* __restrict__ bf1, u16* __restrict__ big, int S)
{
    int jb = blockIdx.x, b = blockIdx.y, tid = threadIdx.x;
    __shared__ float h2[768];
    for (int i = tid; i < 768; i += 256) h2[i] = bf2f(h2buf[(long)b * 768 + i]);
    __syncthreads();
    int col = jb * 256 + tid;
    const u16* wp = W1T + (long)col * 768;
    float a = 0.f;
    for (int k = 0; k < 768; k += 8) {
        short8 wv = *(const short8*)(wp + k);
        #pragma unroll
        for (int q = 0; q < 8; ++q) a += h2[k + q] * bf2f((u16)wv[q]);
    }
    a = fmaxf(a + bf1[col], 0.f);
    big[((long)b * SMAXT + S - 1) * 3072 + col] = f2bf(a);
}

// ---- FFN2(last row) + residual + full decoder + AR update: grid 4
__launch_bounds__(256)
__global__ void ffn2_dec(const u16* __restrict__ big, const u16* __restrict__ W2T,
                         const float* __restrict__ bf2, const float* __restrict__ xbuf,
                         const float* __restrict__ Wd1, const float* __restrict__ bd1,
                         const float* __restrict__ Wd2, const float* __restrict__ bd2,
                         const float* __restrict__ Wd3, const float* __restrict__ bd3,
                         const float* __restrict__ Wpp, const float* __restrict__ bpp,
                         const float* __restrict__ gpp, const float* __restrict__ bepp,
                         float* __restrict__ out, float* __restrict__ Xb, int t)
{
    int b = blockIdx.x, tid = threadIdx.x, lane = tid & 63, w = tid >> 6;
    int S = CCTX + t + 1;
    long row = (long)b * SMAXT + (S - 1);
    __shared__ float bs[3072];
    __shared__ float xr[768];
    __shared__ float tmp[768];
    __shared__ float red[8];
    __shared__ float pp[2];
    for (int i = tid; i < 3072; i += 256) bs[i] = bf2f(big[row * 3072 + i]);
    __syncthreads();
    // FFN2 + residual -> x_last
    #pragma unroll
    for (int u = 0; u < 3; ++u) {
        int col = tid + 256 * u;
        const u16* wp = W2T + (long)col * 3072;
        float a = 0.f;
        for (int k = 0; k < 3072; k += 8) {
            short8 wv = *(const short8*)(wp + k);
            #pragma unroll
            for (int q = 0; q < 8; ++q) a += bs[k + q] * bf2f((u16)wv[q]);
        }
        xr[col] = a + bf2[col] + xbuf[row * 768 + col];
    }
    __syncthreads();
    // d1 = gelu(x @ Wd1 + bd1)
    #pragma unroll
    for (int u = 0; u < 3; ++u) {
        int col = tid + 256 * u;
        float a = 0.f;
        for (int k = 0; k < 768; ++k) a += xr[k] * Wd1[(long)k * 768 + col];
        tmp[col] = gelu_f(a + bd1[col]);
    }
    __syncthreads();
    // d2 = gelu(d1 @ Wd2 + bd2)  (into xr)
    #pragma unroll
    for (int u = 0; u < 3; ++u) {
        int col = tid + 256 * u;
        float a = 0.f;
        for (int k = 0; k < 768; ++k) a += tmp[k] * Wd2[(long)k * 768 + col];
        xr[col] = gelu_f(a + bd2[col]);
    }
    __syncthreads();
    // p = d2 @ Wd3 + bd3
    float a0 = 0.f, a1 = 0.f;
    for (int k = tid; k < 768; k += 256) {
        float v = xr[k];
        a0 += v * Wd3[2 * k]; a1 += v * Wd3[2 * k + 1];
    }
    #pragma unroll
    for (int o = 32; o; o >>= 1) { a0 += __shfl_down(a0, o, 64); a1 += __shfl_down(a1, o, 64); }
    if (!lane) { red[w] = a0; red[4 + w] = a1; }
    __syncthreads();
    if (!tid) {
        float p0 = red[0] + red[1] + red[2] + red[3] + bd3[0];
        float p1 = red[4] + red[5] + red[6] + red[7] + bd3[1];
        out[(long)(b * NFUT + t) * 2 + 0] = p0;
        out[(long)(b * NFUT + t) * 2 + 1] = p1;
        pp[0] = p0; pp[1] = p1;
    }
    __syncthreads();
    if (t == NFUT - 1) return;
    float p0 = pp[0], p1 = pp[1];
    float pv[3]; float s = 0.f;
    #pragma unroll
    for (int u = 0; u < 3; ++u) {
        int col = tid + 256 * u;
        pv[u] = p0 * Wpp[col] + p1 * Wpp[768 + col] + bpp[col];
        s += pv[u];
    }
    #pragma unroll
    for (int o = 32; o; o >>= 1) s += __shfl_down(s, o, 64);
    __syncthreads();
    if (!lane) red[w] = s;
    __syncthreads();
    float mean = (red[0] + red[1] + red[2] + red[3]) * (1.f / 768.f);
    float vs = 0.f;
    #pragma unroll
    for (int u = 0; u < 3; ++u) { float d = pv[u] - mean; vs += d * d; }
    #pragma unroll
    for (int o = 32; o; o >>= 1) vs += __shfl_down(vs, o, 64);
    __syncthreads();
    if (!lane) red[4 + w] = vs;
    __syncthreads();
    float var = (red[4] + red[5] + red[6] + red[7]) * (1.f / 768.f);
    float inv = rsqrtf(var + 1e-5f);
    float* Xr = Xb + ((long)(b * SMAXT + CCTX + t + 1)) * 768;
    #pragma unroll
    for (int u = 0; u < 3; ++u) {
        int col = tid + 256 * u;
        float y = (pv[u] - mean) * inv * gpp[col] + bepp[col];
        if (y > 0.f) Xr[col] += y;
    }
}

// ---------------------------------------------------------------- launch
extern "C" void kernel_launch(void* const* d_in, const int* in_sizes, int n_in,
                              void* d_out, int out_size, void* d_ws, size_t ws_size,
                              hipStream_t stream)
{
    const float* img    = (const float*)d_in[0];
    const float* past   = (const float*)d_in[1];
    const int*   intent = (const int*)d_in[2];
    const float* pos    = (const float*)d_in[3];
    const float* futq   = (const float*)d_in[4];
    const float* iemb   = (const float*)d_in[5];
    const float* temb   = (const float*)d_in[6];
    const float* W_past = (const float*)d_in[7];
    const float* b_past = (const float*)d_in[8];
    const float* W_ppos = (const float*)d_in[9];
    const float* b_ppos = (const float*)d_in[10];
    const float* W_pp   = (const float*)d_in[11];
    const float* b_pp   = (const float*)d_in[12];
    const float* g_pp   = (const float*)d_in[13];
    const float* be_pp  = (const float*)d_in[14];
    const float* Wqkv   = (const float*)d_in[15];
    const float* bqkv   = (const float*)d_in[16];
    const float* Wo     = (const float*)d_in[17];
    const float* bo     = (const float*)d_in[18];
    const float* g1     = (const float*)d_in[19];
    const float* beta1  = (const float*)d_in[20];
    const float* g2     = (const float*)d_in[21];
    const float* beta2  = (const float*)d_in[22];
    const float* W1     = (const float*)d_in[23];
    const float* bf1    = (const float*)d_in[24];
    const float* W2     = (const float*)d_in[25];
    const float* bf2    = (const float*)d_in[26];
    const float* Wd1    = (const float*)d_in[27];
    const float* bd1    = (const float*)d_in[28];
    const float* Wd2    = (const float*)d_in[29];
    const float* bd2    = (const float*)d_in[30];
    const float* Wd3    = (const float*)d_in[31];
    const float* bd3    = (const float*)d_in[32];
    float* out = (float*)d_out;

    float* ws     = (float*)d_ws;
    float* Xb     = ws;                      // 900096 f
    float* xbuf   = ws + 900096;             // 900096 f
    float* qkvbuf = ws + 1800192;            // 2700288 f
    u16*   hbuf   = (u16*)(ws + 4500480);    // 900096 bf16
    u16*   aobuf  = (u16*)(ws + 4950528);    // 900096 bf16
    u16*   big    = (u16*)(ws + 5400576);    // 1172*3072 bf16
    u16*   h2buf  = (u16*)(ws + 7200768);    // 4*768 bf16
    u16*   WqkvT  = (u16*)(ws + 7206912);    // 3*2304*768 bf16
    u16*   WoT    = (u16*)(ws + 9861120);    // 3*768*768
    u16*   W1T    = (u16*)(ws + 10745856);   // 3*768*3072
    u16*   W2T    = (u16*)(ws + 14284800);   // 3*3072*768

    convert_transpose<<<dim3(2304/32, 768/32, 3), 256, 0, stream>>>(Wqkv, WqkvT, 768, 2304);
    convert_transpose<<<dim3(768/32, 768/32, 3), 256, 0, stream>>>(Wo, WoT, 768, 768);
    convert_transpose<<<dim3(3072/32, 768/32, 3), 256, 0, stream>>>(W1, W1T, 768, 3072);
    convert_transpose<<<dim3(768/32, 3072/32, 3), 256, 0, stream>>>(W2, W2T, 3072, 768);

    init_base<<<dim3(MROWS), dim3(256), 0, stream>>>(img, past, intent, pos, futq, iemb,
                                                     temb, W_past, b_past, W_ppos, b_ppos, Xb);

    for (int t = 0; t < NFUT; ++t) {
        int S = CCTX + t + 1;
        const float* src = Xb;
        for (int l = 0; l < 2; ++l) {
            ln_kernel<<<dim3(293), dim3(256), 0, stream>>>(src, g1 + l * 768, beta1 + l * 768, hbuf);
            gemm_mfma<128, 2><<<dim3(18, 10), dim3(256), 0, stream>>>(
                hbuf, WqkvT + (long)l * 768 * 2304, bqkv + l * 2304, nullptr, qkvbuf, MROWS, 2304, 768, 0);
            attn_kernel<<<dim3((S + 15) / 16, 64), dim3(256), 0, stream>>>(qkvbuf, aobuf, S);
            gemm_mfma<64, 0><<<dim3(12, 10), dim3(256), 0, stream>>>(
                aobuf, WoT + (long)l * 768 * 768, bo + l * 768, src, xbuf, MROWS, 768, 768, 0);
            ln_kernel<<<dim3(293), dim3(256), 0, stream>>>(xbuf, g2 + l * 768, beta2 + l * 768, hbuf);
            gemm_mfma<128, 1><<<dim3(24, 10), dim3(256), 0, stream>>>(
                hbuf, W1T + (long)l * 768 * 3072, bf1 + l * 3072, nullptr, big, MROWS, 3072, 768, 0);
            gemm_mfma<64, 0><<<dim3(12, 10), dim3(256), 0, stream>>>(
                big, W2T + (long)l * 3072 * 768, bf2 + l * 768, xbuf, xbuf, MROWS, 768, 3072, 0);
            src = xbuf;
        }
        // ---- layer 2: last-row specialization
        {
            const int l = 2;
            ln_kernel<<<dim3(293), dim3(256), 0, stream>>>(xbuf, g1 + l * 768, beta1 + l * 768, hbuf);
            // K,V for all rows (cols 768..2303)
            gemm_mfma<128, 2><<<dim3(12, 10), dim3(256), 0, stream>>>(
                hbuf, WqkvT + (long)l * 768 * 2304 + (long)768 * 768, bqkv + l * 2304 + 768,
                nullptr, qkvbuf, MROWS, 1536, 768, 768);
            // Q for last rows only
            qkvq_last<<<dim3(12, 4), dim3(256), 0, stream>>>(
                hbuf, WqkvT + (long)l * 768 * 2304, bqkv + l * 2304, qkvbuf, S);
            attn_last<<<dim3(64), dim3(256), 0, stream>>>(qkvbuf, aobuf, S);
            wo_ln_last<<<dim3(4), dim3(256), 0, stream>>>(
                aobuf, WoT + (long)l * 768 * 768, bo + l * 768, xbuf,
                g2 + l * 768, beta2 + l * 768, h2buf, S);
            ffn1_last<<<dim3(12, 4), dim3(256), 0, stream>>>(
                h2buf, W1T + (long)l * 768 * 3072, bf1 + l * 3072, big, S);
            ffn2_dec<<<dim3(4), dim3(256), 0, stream>>>(
                big, W2T + (long)l * 3072 * 768, bf2 + l * 768, xbuf,
                Wd1, bd1, Wd2, bd2, Wd3, bd3, W_pp, b_pp, g_pp, be_pp, out, Xb, t);
        }
    }
}